// Round 9
// baseline (112.156 us; speedup 1.0000x reference)
//
#include <hip/hip_runtime.h>
#include <hip/hip_bf16.h>

typedef __bf16 bf16;
typedef __bf16 bf16x4 __attribute__((ext_vector_type(4)));
typedef __bf16 bf16x8 __attribute__((ext_vector_type(8)));
typedef float f32x4 __attribute__((ext_vector_type(4)));
typedef float f32x16 __attribute__((ext_vector_type(16)));

#define GLOBAL_AS __attribute__((address_space(1)))
#define LDS_AS __attribute__((address_space(3)))

__device__ __forceinline__ void gload_lds16(const void* g, void* l) {
  __builtin_amdgcn_global_load_lds((const GLOBAL_AS void*)g, (LDS_AS void*)l, 16, 0, 0);
}
#define WAITV(n) asm volatile("s_waitcnt vmcnt(" #n ")" ::: "memory")

// ---- prep A: token f32 -> 32-row fragment-major A_pack bf16 (4 MB) ----
// frag fA = wr*4 + mi*2 + kh within (b,t); elem (b*16+t)*8192 + fA*512 + lane*8 + e
// content: token[b*256 + wr*64 + mi*32 + (lane&31)][t*32 + kh*16 + (lane>>5)*8 + e]
// block = (b, wr, t): LDS-transpose 64 rows x 32 k, then write 4 frags.
__global__ __launch_bounds__(256) void pack_a_k(const float* __restrict__ tok,
                                                bf16* __restrict__ o) {
  __shared__ float tile[64][33];
  int bid = blockIdx.x;              // 1024 = b(16) x wr(4) x t(16)
  int t = bid & 15, wr = (bid >> 4) & 3, b = bid >> 6;
  int tid = threadIdx.x;
  {
    int r = tid >> 2, kc = (tid & 3) << 3;
    const float* src = tok + (size_t)(b * 256 + wr * 64 + r) * 512 + t * 32 + kc;
    f32x4 a = *(const f32x4*)src;
    f32x4 c = *(const f32x4*)(src + 4);
    *(f32x4*)&tile[r][kc] = a;
    *(f32x4*)&tile[r][kc + 4] = c;
  }
  __syncthreads();
  int lane = tid & 63, fc = tid >> 6;          // fc = mi*2 + kh
  int mi = fc >> 1, kh = fc & 1;
  bf16x8 p;
#pragma unroll
  for (int e = 0; e < 8; ++e)
    p[e] = (bf16)tile[mi * 32 + (lane & 31)][kh * 16 + ((lane >> 5) << 3) + e];
  *(bf16x8*)(o + ((size_t)(b * 16 + t) * 16 + (wr * 4 + fc)) * 512 + (lane << 3)) = p;
}

// ---- prep B: W f32 -> 32-col fragment-major B_pack bf16 (16 MB) ----
// frag fB = cgrp*2 + kh within (hg,t); elem (hg*16+t)*4096 + fB*512 + lane*8 + e
// content: W[t*32 + kh*16 + (lane>>5)*8 + e][hg*128 + cgrp*32 + (lane&31)]
// block = (jg 64-col group, t): LDS-transpose 32 k x 64 cols, write 4 frags.
__global__ __launch_bounds__(256) void pack_b_k(const float* __restrict__ wsrc,
                                                bf16* __restrict__ o) {
  __shared__ float tile[32][65];
  int bid = blockIdx.x;              // 4096 = jg(256) x t(16)
  int t = bid & 15, jg = bid >> 4;
  int tid = threadIdx.x;
  {
    int r = tid >> 3, c8 = (tid & 7) << 3;
    const float* src = wsrc + (size_t)(t * 32 + r) * 16384 + jg * 64 + c8;
    f32x4 a = *(const f32x4*)src;
    f32x4 c = *(const f32x4*)(src + 4);
    *(f32x4*)&tile[r][c8] = a;
    *(f32x4*)&tile[r][c8 + 4] = c;
  }
  __syncthreads();
  int lane = tid & 63, fc = tid >> 6;          // fc = cgl*2 + kh
  int cgl = fc >> 1, kh = fc & 1;
  bf16x8 p;
#pragma unroll
  for (int e = 0; e < 8; ++e)
    p[e] = (bf16)tile[kh * 16 + ((lane >> 5) << 3) + e][cgl * 32 + (lane & 31)];
  int hg = jg >> 1, half = jg & 1;
  int fB = (half * 2 + cgl) * 2 + kh;
  *(bf16x8*)(o + ((size_t)(hg * 16 + t) * 8 + fB) * 512 + (lane << 3)) = p;
}

// ---- fused main: GEMM1 256x128xK512 via 32x32x16 MFMA (half the LDS
//      bytes/FLOP), frag-linear LDS, BK=32 triple-buffer (R3 sync) ----
// grid (hg=128, b=16), 512 thr = 8 waves (wr=w>>1, wc=w&1), 64x64/wave.
// LDS 72 KB: 3 x 24 KB GEMM bufs (A 16K + B 8K); epilogue reuses [0,64K).
__global__ __launch_bounds__(512, 4) void fused_main_k(
    const bf16* __restrict__ Ap, const bf16* __restrict__ Bp,
    const float* __restrict__ bias, float* __restrict__ out) {
  __shared__ char smem[73728];
  const int tid = threadIdx.x;
  const int lane = tid & 63;
  const int w = tid >> 6;
  const int wr = w >> 1;   // 0..3 (64-row group)
  const int wc = w & 1;    // 0..1 (64-col group)
  const int b = blockIdx.y;
  const int hg = blockIdx.x;
  const int j0 = hg << 7;

  const bf16* Abase = Ap + ((size_t)b << 17);          // + t*8192 elems
  const bf16* Bbase = Bp + ((size_t)hg << 16);         // + t*4096 elems

  f32x16 acc[2][2] = {};

#define STAGE(t_, buf_) do { \
    gload_lds16(Abase + ((size_t)(t_) << 13) + (tid << 3), \
                smem + (buf_) * 24576 + tid * 16); \
    gload_lds16(Abase + ((size_t)(t_) << 13) + ((tid + 512) << 3), \
                smem + (buf_) * 24576 + (tid + 512) * 16); \
    gload_lds16(Bbase + ((size_t)(t_) << 12) + (tid << 3), \
                smem + (buf_) * 24576 + 16384 + tid * 16); \
  } while (0)

  STAGE(0, 0);
  STAGE(1, 1);
  WAITV(3);  // tile0's 3 loads landed; tile1's 3 in flight
  __builtin_amdgcn_s_barrier();
  asm volatile("" ::: "memory");

  // ---- K-loop: 16 steps of BK=32 ----
#pragma unroll
  for (int t = 0; t < 16; ++t) {
    const int cb = (t % 3) * 24576;
    if (t < 14) STAGE(t + 2, (t + 2) % 3);
    bf16x8 af[2][2], bf[2][2];
#pragma unroll
    for (int mi = 0; mi < 2; ++mi)
#pragma unroll
      for (int kh = 0; kh < 2; ++kh)
        af[mi][kh] = *(const bf16x8*)(smem + cb +
            ((wr * 4 + mi * 2 + kh) << 10) + (lane << 4));
#pragma unroll
    for (int ni = 0; ni < 2; ++ni)
#pragma unroll
      for (int kh = 0; kh < 2; ++kh)
        bf[ni][kh] = *(const bf16x8*)(smem + cb + 16384 +
            (((wc * 2 + ni) * 2 + kh) << 10) + (lane << 4));
    __builtin_amdgcn_s_setprio(1);
#pragma unroll
    for (int kh = 0; kh < 2; ++kh)
#pragma unroll
      for (int mi = 0; mi < 2; ++mi)
#pragma unroll
        for (int ni = 0; ni < 2; ++ni)
          acc[mi][ni] = __builtin_amdgcn_mfma_f32_32x32x16_bf16(
              af[mi][kh], bf[ni][kh], acc[mi][ni], 0, 0, 0);
    __builtin_amdgcn_s_setprio(0);
    asm volatile("" ::: "memory");
    if (t < 14) { WAITV(3); } else if (t == 14) { WAITV(0); }
    __builtin_amdgcn_s_barrier();
    asm volatile("" ::: "memory");
  }
#undef STAGE

  // ---- epilogue: bias + silu + rope (32x32 C/D: col=lane&31,
  //      row=(r&3)+8*(r>>2)+4*(lane>>5)); k/v bf16 -> LDS [h][d][n] ----
  {
    const int d31 = lane & 31;
    const int dd = lane & 15;
    const bool isk = d31 < 16;
    const float sgn = (d31 & 1) ? 1.0f : -1.0f;
#pragma unroll
    for (int ni = 0; ni < 2; ++ni) {
      const int hl = wc * 2 + ni;                 // 0..3 local channel
      const int col = wc * 64 + ni * 32 + d31;    // 0..127
      const float bv = bias[j0 + col];
      float freq = 0.f;
      if (isk) {
        const int tp = dd >> 1;
        const int hglob = (hg << 2) + hl;
        freq = exp2f((float)(hglob * 8 + tp) * (-13.287712379549449f / 4096.0f));
      }
#pragma unroll
      for (int mi = 0; mi < 2; ++mi) {
        f32x16 c = acc[mi][ni];
#pragma unroll
        for (int r = 0; r < 16; ++r) {
          float x = c[r] + bv;
          if (isk) x = x * __builtin_amdgcn_rcpf(1.0f + __expf(-x));  // silu
          c[r] = x;
        }
        if (isk) {
#pragma unroll
          for (int r = 0; r < 16; ++r) {
            float partner = __shfl_xor(c[r], 1);  // d-pair partner (lane^1)
            int n = wr * 64 + mi * 32 + (r & 3) + ((r >> 2) << 3) + ((lane >> 5) << 2);
            float sv, cv;
            __sincosf(freq * (float)(255 - n), &sv, &cv);
            c[r] = c[r] * cv + sgn * partner * sv;
          }
        }
#pragma unroll
        for (int q = 0; q < 4; ++q) {
          bf16x4 pk;
          pk[0] = (bf16)c[q * 4 + 0]; pk[1] = (bf16)c[q * 4 + 1];
          pk[2] = (bf16)c[q * 4 + 2]; pk[3] = (bf16)c[q * 4 + 3];
          int n0 = wr * 64 + mi * 32 + (q << 3) + ((lane >> 5) << 2);
          int byte = (isk ? 0 : 32768) + hl * 8192 + dd * 512 + n0 * 2;
          byte ^= ((dd & 7) << 4);  // bank swizzle
          *(bf16x4*)(smem + byte) = pk;
        }
      }
    }
  }
  __syncthreads();

  // ---- GEMM2 (R1-verbatim): wave w -> head hl=w>>1, n-half=w&1 ----
  {
    const int hl = w >> 1;
    const int half = w & 1;
    const int dd = lane & 15;
    f32x4 d2 = {0.f, 0.f, 0.f, 0.f};
#pragma unroll
    for (int kk = 0; kk < 4; ++kk) {
      const int n0 = half * 128 + kk * 32 + ((lane >> 4) << 3);
      int byte = hl * 8192 + dd * 512 + n0 * 2;
      byte ^= ((dd & 7) << 4);
      bf16x8 ka = *(const bf16x8*)(smem + byte);           // k^T: [d][n]
      bf16x8 vb = *(const bf16x8*)(smem + 32768 + byte);   // v:   [e][n]
      d2 = __builtin_amdgcn_mfma_f32_16x16x32_bf16(ka, vb, d2, 0, 0, 0);
    }
    __syncthreads();  // all k/v reads done before partials overwrite
    float* part = (float*)smem;  // [8][256]
#pragma unroll
    for (int j = 0; j < 4; ++j) {
      int de = (((lane >> 4) << 2) + j) * 16 + dd;  // d*16+e
      part[w * 256 + de] = d2[j];
    }
  }
  __syncthreads();

  // ---- combine wave-pair partials, coalesced float4 store ----
  if (tid < 256) {
    const float* part = (const float*)smem;
    f32x4 o;
#pragma unroll
    for (int hl = 0; hl < 4; ++hl)
      o[hl] = part[(2 * hl) * 256 + tid] + part[(2 * hl + 1) * 256 + tid];
    *(f32x4*)(out + (size_t)b * 131072 + (size_t)tid * 512 + hg * 4) = o;
  }
}

extern "C" void kernel_launch(void* const* d_in, const int* in_sizes, int n_in,
                              void* d_out, int out_size, void* d_ws, size_t ws_size,
                              hipStream_t stream) {
  const float* token = (const float*)d_in[0];   // (16,256,512) f32
  const float* W     = (const float*)d_in[1];   // (512,16384) f32
  const float* bias  = (const float*)d_in[2];   // (16384,) f32
  float* out = (float*)d_out;                   // (16,256,512) f32

  bf16* Apack = (bf16*)d_ws;                                    // 4 MB
  bf16* Bpack = (bf16*)((char*)d_ws + (size_t)4 * 1024 * 1024); // 16 MB

  pack_a_k<<<1024, 256, 0, stream>>>(token, Apack);
  pack_b_k<<<4096, 256, 0, stream>>>(W, Bpack);
  fused_main_k<<<dim3(128, 16), 512, 0, stream>>>(Apack, Bpack, bias, out);
}